// Round 12
// baseline (404.974 us; speedup 1.0000x reference)
//
#include <hip/hip_runtime.h>
#include <cmath>

#define SS 45
#define FSPLIT 16

typedef __attribute__((ext_vector_type(8))) _Float16 half8;
typedef __attribute__((ext_vector_type(4))) float float4v;
typedef __attribute__((ext_vector_type(8))) unsigned short ushort8v;

__device__ inline unsigned short f16b(float f) {
    union { _Float16 h; unsigned short u; } c;
    c.h = (_Float16)f;
    return c.u;
}
__device__ inline float f16back(unsigned short u) {
    union { _Float16 h; unsigned short u; } c;
    c.u = u;
    return (float)c.h;
}

__device__ __forceinline__ void async16(const void* g, void* l) {
    __builtin_amdgcn_global_load_lds(
        (const __attribute__((address_space(1))) void*)g,
        (__attribute__((address_space(3))) void*)l, 16, 0, 0);
}

// DPP cross-lane reduce helpers (VALU pipe). 0xB1=xor1, 0x4E=xor2,
// 0x141=row_half_mirror (xor7 within 8), 0x128=row_ror:8 (xor8 within 16).
template <int CTRL>
__device__ __forceinline__ float dppadd(float v) {
    int x = __builtin_amdgcn_mov_dpp(__float_as_int(v), CTRL, 0xF, 0xF, true);
    return v + __int_as_float(x);
}
template <int CTRL>
__device__ __forceinline__ float dppmax(float v) {
    int x = __builtin_amdgcn_mov_dpp(__float_as_int(v), CTRL, 0xF, 0xF, true);
    return fmaxf(v, __int_as_float(x));
}

// monotonic float->uint mapping: order-preserving for all finite floats
__device__ __forceinline__ unsigned int fmono(float f) {
    unsigned int u = __float_as_uint(f);
    return (u & 0x80000000u) ? ~u : (u | 0x80000000u);
}

// ---- W -> WT hi/lo transpose + vmp zero ---------------------------------------
__global__ __launch_bounds__(256) void convW_kernel(
    const float* __restrict__ Wq, const float* __restrict__ Wk, const float* __restrict__ Wv,
    unsigned short* __restrict__ WTh, unsigned short* __restrict__ WTl,
    float* __restrict__ vmp)
{
    int bid = blockIdx.x;
    if (bid < 768) {
        int zy = bid >> 8;
        int bxy = bid & 255;
        const float* W = (zy == 0) ? Wq : (zy == 1) ? Wk : Wv;
        unsigned short* th = WTh + (size_t)zy * 262144;
        unsigned short* tl = WTl + (size_t)zy * 262144;
        __shared__ float t[32][33];
        int bx = bxy & 15, by = bxy >> 4;
        int tx = threadIdx.x & 31, ty = threadIdx.x >> 5;
        for (int i = ty; i < 32; i += 8) t[i][tx] = W[(size_t)(by * 32 + i) * 512 + bx * 32 + tx];
        __syncthreads();
        for (int i = ty; i < 32; i += 8) {
            float f = t[tx][i];
            unsigned short h = f16b(f);
            unsigned short lo = f16b(f - f16back(h));
            th[(size_t)(bx * 32 + i) * 512 + by * 32 + tx] = h;
            tl[(size_t)(bx * 32 + i) * 512 + by * 32 + tx] = lo;
        }
    } else {
        for (int i = threadIdx.x; i < 2048; i += 256) vmp[i] = 0.f;
    }
}

// ---- fused x-conversion + Q,K,V projection + vmean partial --------------------
// EXACT R4 qkv8 (measured ~89-90 us, 5x reproduced). qkv frontier locked.
__global__ __launch_bounds__(512, 2) void qkv8_kernel(
    const float* __restrict__ X,
    const unsigned short* __restrict__ WTh, const unsigned short* __restrict__ WTl,
    float* __restrict__ Q, float* __restrict__ K, float* __restrict__ V,
    float* __restrict__ vmp)
{
    __shared__ unsigned short lds[73728];   // 2 buffers * 36864 shorts (144 KB)

    int wave = threadIdx.x >> 6;            // 0..7
    int lane = threadIdx.x & 63;
    int m0blk = blockIdx.x * 256;
    int n0blk = blockIdx.y * 128;
    int fr = lane & 15;
    int C = lane >> 4;
    int srow = lane >> 2;
    int sslot = lane & 3;
    int mrb = (wave >> 1) * 64;             // 4 wave-rows
    int nrb = (wave & 1) * 64;              // 2 wave-cols

    const unsigned short* gbB[5];
    gbB[0] = WTh;
    gbB[1] = WTl;
    gbB[2] = WTh + 262144;
    gbB[3] = WTl + 262144;
    gbB[4] = WTh + 524288;

    int rloc0 = wave * 32 + srow;
    int rloc1 = wave * 32 + 16 + srow;
    int Cp0 = sslot ^ ((rloc0 >> 1) & 3);
    int Cp1 = sslot ^ ((rloc1 >> 1) & 3);
    const float* xr0 = X + (size_t)(m0blk + rloc0) * 512 + Cp0 * 8;
    const float* xr1 = X + (size_t)(m0blk + rloc1) * 512 + Cp1 * 8;

    float4v accq[4][4], acck[4][4], accv[4][4];
    #pragma unroll
    for (int i = 0; i < 4; i++)
        #pragma unroll
        for (int j = 0; j < 4; j++) {
            accq[i][j] = (float4v){0.f, 0.f, 0.f, 0.f};
            acck[i][j] = (float4v){0.f, 0.f, 0.f, 0.f};
            accv[i][j] = (float4v){0.f, 0.f, 0.f, 0.f};
        }

    auto stageB = [&](int buf, int k0) {
        int rloc = wave * 16 + srow;
        int Cp = sslot ^ ((rloc >> 1) & 3);
        #pragma unroll
        for (int t = 0; t < 5; t++) {
            const unsigned short* g = gbB[t] + (size_t)(n0blk + rloc) * 512 + k0 + Cp * 8;
            async16(g, lds + buf * 36864 + 16384 + t * 4096 + wave * 512);
        }
    };

    float4 xv[2][2];
    auto loadX = [&](int k0) {
        xv[0][0] = *(const float4*)(xr0 + k0);
        xv[0][1] = *(const float4*)(xr0 + k0 + 4);
        xv[1][0] = *(const float4*)(xr1 + k0);
        xv[1][1] = *(const float4*)(xr1 + k0 + 4);
    };
    auto writeA = [&](int buf) {
        #pragma unroll
        for (int inst = 0; inst < 2; inst++) {
            const float* f = (const float*)&xv[inst][0];
            ushort8v hv, lv;
            #pragma unroll
            for (int e = 0; e < 8; e++) {
                unsigned short h = f16b(f[e]);
                hv[e] = h;
                lv[e] = f16b(f[e] - f16back(h));
            }
            unsigned short* dsth = lds + buf * 36864 + (wave * 32 + inst * 16) * 32 + lane * 8;
            *(ushort8v*)dsth = hv;
            *(ushort8v*)(dsth + 8192) = lv;
        }
    };

    // prologue: stage tile 0 fully
    loadX(0);
    stageB(0, 0);
    writeA(0);
    asm volatile("s_waitcnt vmcnt(0)" ::: "memory");
    asm volatile("s_waitcnt lgkmcnt(0)" ::: "memory");
    __builtin_amdgcn_s_barrier();

    for (int kk = 0; kk < 16; kk++) {
        const unsigned short* Lb = lds + (kk & 1) * 36864;
        int nbuf = (kk + 1) & 1;
        int nk0 = (kk + 1) * 32;

        if (kk < 15) {
            loadX(nk0);          // x(k+1) -> regs (HBM latency hides under MFMA)
            stageB(nbuf, nk0);   // B(k+1) -> LDS async
        }

        half8 A_h[4], A_l[4];
        #pragma unroll
        for (int i = 0; i < 4; i++) {
            int R = mrb + i * 16 + fr;
            int sl = C ^ ((R >> 1) & 3);
            A_h[i] = *(const half8*)(Lb + R * 32 + sl * 8);
            A_l[i] = *(const half8*)(Lb + 8192 + R * 32 + sl * 8);
        }
        #pragma unroll
        for (int j = 0; j < 4; j++) {
            int R = nrb + j * 16 + fr;
            int sl = C ^ ((R >> 1) & 3);
            int off = R * 32 + sl * 8;
            half8 Bqh = *(const half8*)(Lb + 16384 + off);
            half8 Bql = *(const half8*)(Lb + 20480 + off);
            half8 Bkh = *(const half8*)(Lb + 24576 + off);
            half8 Bkl = *(const half8*)(Lb + 28672 + off);
            half8 Bvh = *(const half8*)(Lb + 32768 + off);
            #pragma unroll
            for (int i = 0; i < 4; i++) {
                accq[i][j] = __builtin_amdgcn_mfma_f32_16x16x32_f16(A_h[i], Bqh, accq[i][j], 0, 0, 0);
                accq[i][j] = __builtin_amdgcn_mfma_f32_16x16x32_f16(A_h[i], Bql, accq[i][j], 0, 0, 0);
                accq[i][j] = __builtin_amdgcn_mfma_f32_16x16x32_f16(A_l[i], Bqh, accq[i][j], 0, 0, 0);
                acck[i][j] = __builtin_amdgcn_mfma_f32_16x16x32_f16(A_h[i], Bkh, acck[i][j], 0, 0, 0);
                acck[i][j] = __builtin_amdgcn_mfma_f32_16x16x32_f16(A_h[i], Bkl, acck[i][j], 0, 0, 0);
                acck[i][j] = __builtin_amdgcn_mfma_f32_16x16x32_f16(A_l[i], Bkh, acck[i][j], 0, 0, 0);
                accv[i][j] = __builtin_amdgcn_mfma_f32_16x16x32_f16(A_h[i], Bvh, accv[i][j], 0, 0, 0);
            }
        }

        if (kk < 15) {
            writeA(nbuf);        // compiler inserts vmcnt wait for xv regs here
            asm volatile("s_waitcnt vmcnt(0)" ::: "memory");    // B(k+1) landed
            asm volatile("s_waitcnt lgkmcnt(0)" ::: "memory");  // A-writes + reads drained
            __builtin_amdgcn_s_barrier();                       // publish buf k+1
        }
    }

    // ---- vmean partial: sum accv over (i,r), then over C-groups (rows) --------
    int hh = n0blk + nrb;            // col base; one head per wave
    int hd = hh >> 6;                // head index
    int bb0 = (m0blk + mrb) >> 12;   // batch (64-row wave tile never crosses)
    {
        float cs[4];
        #pragma unroll
        for (int j = 0; j < 4; j++) {
            float s = 0.f;
            #pragma unroll
            for (int i = 0; i < 4; i++)
                #pragma unroll
                for (int r = 0; r < 4; r++) s += accv[i][j][r];
            s += __shfl_xor(s, 16, 64);
            s += __shfl_xor(s, 32, 64);
            cs[j] = s;
        }
        if (C == 0) {
            #pragma unroll
            for (int j = 0; j < 4; j++)
                atomicAdd(vmp + ((size_t)(bb0 * 8 + hd) * 64) + j * 16 + fr, cs[j]);
        }
    }

    // ---- epilogue: C/D layout col=lane&15, row=(lane>>4)*4+reg ----------------
    int rbase = C * 4;
    int m0 = m0blk + mrb;
    #pragma unroll
    for (int i = 0; i < 4; i++)
        #pragma unroll
        for (int r = 0; r < 4; r++) {
            int rg = m0 + i * 16 + rbase + r;
            int bb = rg >> 12, l = rg & 4095;
            size_t rowoff = ((size_t)(bb * 8 + hd) * 4096 + l) * 64;
            #pragma unroll
            for (int j = 0; j < 4; j++) Q[rowoff + j * 16 + fr] = accq[i][j][r];
            #pragma unroll
            for (int j = 0; j < 4; j++) K[rowoff + j * 16 + fr] = acck[i][j][r];
            #pragma unroll
            for (int j = 0; j < 4; j++) V[rowoff + j * 16 + fr] = accv[i][j][r];
        }
}

// ---------------- M = max_s - mean_s of sampled dots, fp32 ---------------------
// R12: grid coarsened 32768 -> 8192 blocks; each wave processes 4 insts
// sequentially (per-inst code identical -> M bit-identical). Theory: total
// floor-sum ~200us vs measured 400us -> dispatch overhead on 41K tiny
// workgroups is the prime unexplained-cost candidate.
__global__ __launch_bounds__(256) void m_kernel(
    const float* __restrict__ Q, const float* __restrict__ K,
    const int* __restrict__ idx, float* __restrict__ M)
{
    int wave = threadIdx.x >> 6;
    int lane = threadIdx.x & 63;
    int g = lane >> 3;
    int t = lane & 7;
    int inst0 = blockIdx.x * 16 + wave * 4;
    for (int ii = 0; ii < 4; ii++) {
        int inst = inst0 + ii;
        int bh = inst >> 12;
        int l = inst & 4095;
        float4 qa = *(const float4*)(Q + (size_t)inst * 64 + t * 4);
        float4 qb = *(const float4*)(Q + (size_t)inst * 64 + 32 + t * 4);
        const float* kb = K + (size_t)bh * 4096 * 64;
        const int* irow = idx + (size_t)l * SS;
        int jv[6];
        #pragma unroll
        for (int it = 0; it < 6; it++) {
            int s = it * 8 + g;
            jv[it] = irow[(it == 5 && g >= 5) ? 0 : s];
        }
        float4 kva[6], kvb[6];
        #pragma unroll
        for (int it = 0; it < 6; it++) {
            kva[it] = *(const float4*)(kb + (size_t)jv[it] * 64 + t * 4);
            kvb[it] = *(const float4*)(kb + (size_t)jv[it] * 64 + 32 + t * 4);
        }
        float maxv = -1e30f, sum = 0.f, p0 = 0.f;
        #pragma unroll
        for (int it = 0; it < 6; it++) {
            float p = qa.x * kva[it].x;
            p = fmaf(qa.y, kva[it].y, p);
            p = fmaf(qa.z, kva[it].z, p);
            p = fmaf(qa.w, kva[it].w, p);
            p = fmaf(qb.x, kvb[it].x, p);
            p = fmaf(qb.y, kvb[it].y, p);
            p = fmaf(qb.z, kvb[it].z, p);
            p = fmaf(qb.w, kvb[it].w, p);
            p = dppadd<0xB1>(p);
            p = dppadd<0x4E>(p);
            p = dppadd<0x141>(p);
            if (it == 0) p0 = p;
            maxv = fmaxf(maxv, p);
            sum += p;
        }
        maxv = dppmax<0x128>(maxv);
        maxv = fmaxf(maxv, __shfl_xor(maxv, 16, 64));
        maxv = fmaxf(maxv, __shfl_xor(maxv, 32, 64));
        sum = dppadd<0x128>(sum);
        sum += __shfl_xor(sum, 16, 64);
        sum += __shfl_xor(sum, 32, 64);
        float p0b = __shfl(p0, 0, 64);
        if (lane == 0) M[inst] = maxv - (sum - 3.f * p0b) * (1.f / 45.f);
    }
}

// ---------------- topk phase 1: per-512-chunk bitonic top-45 -------------------
__global__ __launch_bounds__(256) void topk_local_kernel(
    const float* __restrict__ M, unsigned long long* __restrict__ cand)
{
    int chunk = blockIdx.x;
    int bh = chunk >> 3, c = chunk & 7;
    __shared__ unsigned long long keys[512];
    int tid = threadIdx.x;
    for (int i = tid; i < 512; i += 256) {
        int l = c * 512 + i;
        unsigned int u = fmono(M[(size_t)bh * 4096 + l]);
        keys[i] = ((unsigned long long)u << 32) | (unsigned int)(4095 - l);
    }
    __syncthreads();
    for (int k = 2; k <= 512; k <<= 1)
        for (int j = k >> 1; j > 0; j >>= 1) {
            for (int i0 = tid; i0 < 512; i0 += 256) {
                int ixj = i0 ^ j;
                if (ixj > i0) {
                    unsigned long long a = keys[i0], b = keys[ixj];
                    bool asc = (i0 & k) != 0;
                    if (asc ? (a > b) : (a < b)) { keys[i0] = b; keys[ixj] = a; }
                }
            }
            __syncthreads();
        }
    if (tid < SS) cand[(size_t)chunk * SS + tid] = keys[tid];
}

// ---------------- topk phase 2: merge 8x45 candidates + base (merged) ----------
__global__ __launch_bounds__(256) void topk_merge_base_kernel(
    const unsigned long long* __restrict__ cand, int* __restrict__ tidx,
    const float* __restrict__ vmp, const float* __restrict__ Wo,
    float* __restrict__ vmean, float* __restrict__ base)
{
    int bid = blockIdx.x;
    int tid = threadIdx.x;
    if (bid < 32) {
        __shared__ unsigned long long keys[512];
        for (int i = tid; i < 512; i += 256) {
            unsigned long long v = 0ull;   // pad: sorts below all real floats
            if (i < 8 * SS) {
                int cc = i / SS, r = i - cc * SS;
                v = cand[((size_t)bid * 8 + cc) * SS + r];
            }
            keys[i] = v;
        }
        __syncthreads();
        for (int k = 2; k <= 512; k <<= 1)
            for (int j = k >> 1; j > 0; j >>= 1) {
                for (int i0 = tid; i0 < 512; i0 += 256) {
                    int ixj = i0 ^ j;
                    if (ixj > i0) {
                        unsigned long long a = keys[i0], b = keys[ixj];
                        bool asc = (i0 & k) != 0;
                        if (asc ? (a > b) : (a < b)) { keys[i0] = b; keys[ixj] = a; }
                    }
                }
                __syncthreads();
            }
        if (tid < SS) tidx[bid * SS + tid] = 4095 - (int)(keys[tid] & 0xFFFFFFFFu);
    } else {
        int b = bid - 32;
        __shared__ float vmS[512];
        for (int i = tid; i < 512; i += 256) {
            float s = vmp[(size_t)b * 512 + i] * (1.f / 4096.f);
            vmS[i] = s;
            vmean[(size_t)b * 512 + i] = s;
        }
        __syncthreads();
        for (int jj = tid; jj < 512; jj += 256) {
            float s = 0.f;
            for (int i = 0; i < 512; i++) s += vmS[i] * Wo[(size_t)i * 512 + jj];
            base[(size_t)b * 512 + jj] = s;
        }
    }
}

// ---------------- flash attention over selected queries + fill (merged) --------
// attn part: R11 structure (256 threads, 16 groups x 3 rows, pad-68).
// fill part (R12): coarsened 8192 -> 2048 blocks, 4 float4/thread (dispatch
// overhead reduction; mapping/values identical).
__global__ __launch_bounds__(256) void attn_fill_kernel(
    const float* __restrict__ Q, const float* __restrict__ K, const float* __restrict__ V,
    const int* __restrict__ tidx,
    float* __restrict__ Opart, float* __restrict__ mpart, float* __restrict__ lpart,
    const float4* __restrict__ base4, float4* __restrict__ out4)
{
    int bid = blockIdx.x;
    if (bid >= 512) {
        int i0 = (bid - 512) * 1024 + threadIdx.x;
        #pragma unroll
        for (int k = 0; k < 4; k++) {
            int i = i0 + k * 256;
            int b = i >> 19;
            int j4 = i & 127;
            out4[i] = base4[b * 128 + j4];
        }
        return;
    }
    int split = bid & 15;
    int bh = bid >> 4;
    int L0 = split * (4096 / FSPLIT);

    __shared__ float Qs[48][68];
    __shared__ float Ks[64][68];
    __shared__ float Vs[64][68];
    __shared__ float Ps[48][68];
    __shared__ int tS[48];

    int tid = threadIdx.x;
    int lane = tid & 63, w = tid >> 6;
    if (tid < 48) tS[tid] = (tid < SS) ? tidx[bh * SS + tid] : 0;
    __syncthreads();
    for (int u = w; u < 48; u += 4)
        Qs[u][lane] = Q[((size_t)bh * 4096 + tS[u]) * 64 + lane];

    int ug = tid >> 4, lg = tid & 15;   // 16 groups x 3 rows = 48 queries
    float mrun[3], lrun[3], O[3][4];
    #pragma unroll
    for (int i = 0; i < 3; i++) {
        mrun[i] = -1e30f; lrun[i] = 0.f;
        #pragma unroll
        for (int j = 0; j < 4; j++) O[i][j] = 0.f;
    }

    for (int tt = 0; tt < 4096 / FSPLIT / 64; tt++) {
        int lbase = L0 + tt * 64;
        if (tt > 0) __syncthreads();
        for (int r = w; r < 64; r += 4) {
            Ks[r][lane] = K[((size_t)bh * 4096 + lbase + r) * 64 + lane];
            Vs[r][lane] = V[((size_t)bh * 4096 + lbase + r) * 64 + lane];
        }
        __syncthreads();

        {
            float acc[3][4];
            #pragma unroll
            for (int i = 0; i < 3; i++)
                #pragma unroll
                for (int j = 0; j < 4; j++) acc[i][j] = 0.f;
            for (int d0 = 0; d0 < 64; d0 += 4) {
                float4 a[3], b[4];
                #pragma unroll
                for (int i = 0; i < 3; i++) a[i] = *(float4*)&Qs[ug * 3 + i][d0];
                #pragma unroll
                for (int j = 0; j < 4; j++) b[j] = *(float4*)&Ks[lg * 4 + j][d0];
                #pragma unroll
                for (int i = 0; i < 3; i++)
                    #pragma unroll
                    for (int j = 0; j < 4; j++)
                        acc[i][j] += a[i].x * b[j].x + a[i].y * b[j].y + a[i].z * b[j].z + a[i].w * b[j].w;
            }
            #pragma unroll
            for (int i = 0; i < 3; i++) {
                #pragma unroll
                for (int j = 0; j < 4; j++) acc[i][j] *= 0.125f;
                float tm = fmaxf(fmaxf(acc[i][0], acc[i][1]), fmaxf(acc[i][2], acc[i][3]));
                tm = fmaxf(tm, __shfl_xor(tm, 1, 64));
                tm = fmaxf(tm, __shfl_xor(tm, 2, 64));
                tm = fmaxf(tm, __shfl_xor(tm, 4, 64));
                tm = fmaxf(tm, __shfl_xor(tm, 8, 64));
                float nm = fmaxf(mrun[i], tm);
                float corr = __expf(mrun[i] - nm);
                float rs = 0.f;
                #pragma unroll
                for (int j = 0; j < 4; j++) {
                    float p = __expf(acc[i][j] - nm);
                    Ps[ug * 3 + i][lg * 4 + j] = p;
                    rs += p;
                }
                rs += __shfl_xor(rs, 1, 64);
                rs += __shfl_xor(rs, 2, 64);
                rs += __shfl_xor(rs, 4, 64);
                rs += __shfl_xor(rs, 8, 64);
                lrun[i] = lrun[i] * corr + rs;
                mrun[i] = nm;
                #pragma unroll
                for (int j = 0; j < 4; j++) O[i][j] *= corr;
            }
        }
        __syncthreads();

        {
            for (int l0 = 0; l0 < 64; l0 += 4) {
                float4 vr[4];
                #pragma unroll
                for (int r = 0; r < 4; r++) vr[r] = *(float4*)&Vs[l0 + r][lg * 4];
                #pragma unroll
                for (int i = 0; i < 3; i++) {
                    float4 pv = *(float4*)&Ps[ug * 3 + i][l0];
                    #pragma unroll
                    for (int j = 0; j < 4; j++) {
                        float vj0 = (&vr[0].x)[j], vj1 = (&vr[1].x)[j];
                        float vj2 = (&vr[2].x)[j], vj3 = (&vr[3].x)[j];
                        O[i][j] = fmaf(pv.x, vj0, fmaf(pv.y, vj1, fmaf(pv.z, vj2, fmaf(pv.w, vj3, O[i][j]))));
                    }
                }
            }
        }
    }

    {
        #pragma unroll
        for (int i = 0; i < 3; i++) {
            int u = ug * 3 + i;
            if (u < SS) {
                size_t pbase = ((size_t)(bh * FSPLIT + split) * SS + u);
                if (lg == 0) { mpart[pbase] = mrun[i]; lpart[pbase] = lrun[i]; }
                #pragma unroll
                for (int j = 0; j < 4; j++)
                    Opart[pbase * 64 + lg * 4 + j] = O[i][j];
            }
        }
    }
}

// ---------------- combine splits + delta@Wo + scatter into out -----------------
__global__ __launch_bounds__(256) void combine_kernel(
    const float* __restrict__ Opart, const float* __restrict__ mpart, const float* __restrict__ lpart,
    const float* __restrict__ vmean, const float* __restrict__ Wo,
    const int* __restrict__ tidx, float* __restrict__ out)
{
    int rr = blockIdx.x;
    int bh = rr / SS, u = rr % SS;
    int h = bh & 7, b = bh >> 3;
    __shared__ float dS[64];
    int tid = threadIdx.x;
    if (tid < 64) {
        float m = -1e30f;
        #pragma unroll
        for (int s = 0; s < FSPLIT; s++)
            m = fmaxf(m, mpart[(size_t)(bh * FSPLIT + s) * SS + u]);
        float den = 0.f, num = 0.f;
        #pragma unroll
        for (int s = 0; s < FSPLIT; s++) {
            size_t pbase = (size_t)(bh * FSPLIT + s) * SS + u;
            float wgt = __expf(mpart[pbase] - m);
            den += wgt * lpart[pbase];
            num += wgt * Opart[pbase * 64 + tid];
        }
        dS[tid] = num / den - vmean[(size_t)bh * 64 + tid];
    }
    __syncthreads();
    int l = tidx[rr];
    float* orow = out + ((size_t)b * 4096 + l) * 512;
    for (int j = tid; j < 512; j += 256) {
        float s = 0.f;
        #pragma unroll
        for (int dd = 0; dd < 64; dd++) s += dS[dd] * Wo[(size_t)(h * 64 + dd) * 512 + j];
        atomicAdd(orow + j, s);
    }
}

extern "C" void kernel_launch(void* const* d_in, const int* in_sizes, int n_in,
                              void* d_out, int out_size, void* d_ws, size_t ws_size,
                              hipStream_t stream)
{
    const float* x  = (const float*)d_in[0];
    const float* Wq = (const float*)d_in[1];
    const float* Wk = (const float*)d_in[2];
    const float* Wv = (const float*)d_in[3];
    const float* Wo = (const float*)d_in[4];
    const int*  idx = (const int*)d_in[5];
    float* out = (float*)d_out;

    float* W = (float*)d_ws;
    float* Q = W;                        // 8,388,608 f
    float* K = W + 8388608;              // 8,388,608 f
    float* V = W + 16777216;             // 8,388,608 f
    unsigned short* WTh = (unsigned short*)(W + 33554432);
    unsigned short* WTl = (unsigned short*)(W + 33947648);  // ends 34340864 f
    float* vmp = W + 34340864;           // 2,048 f (live DURING qkv8 -> own space)
    // total 34,342,912 f = 137.4 MB

    float* Mv    = W + 25165824;         // 131,072
    float* Opart = W + 25296896;         // 1,474,560
    float* mpart = W + 26771456;         // 23,040
    float* lpart = W + 26794496;         // 23,040
    float* vmean = W + 33439744;         // 2,048
    float* base  = W + 33441792;         // 2,048
    int*   tidx  = (int*)(W + 33443840); // 1,440 ints -> ends 33445280
    unsigned long long* cand = (unsigned long long*)(W + 33445280); // 256*45 u64

    convW_kernel<<<769, 256, 0, stream>>>(Wq, Wk, Wv, WTh, WTl, vmp);
    qkv8_kernel<<<dim3(64, 4), 512, 0, stream>>>(x, WTh, WTl, Q, K, V, vmp);
    m_kernel<<<8192, 256, 0, stream>>>(Q, K, idx, Mv);
    topk_local_kernel<<<256, 256, 0, stream>>>(Mv, cand);
    topk_merge_base_kernel<<<36, 256, 0, stream>>>(cand, tidx, vmp, Wo, vmean, base);
    attn_fill_kernel<<<512 + 2048, 256, 0, stream>>>(Q, K, V, tidx, Opart, mpart, lpart,
                                                     (const float4*)base, (float4*)out);
    combine_kernel<<<1440, 256, 0, stream>>>(Opart, mpart, lpart, vmean, Wo, tidx, out);
}

// Round 13
// 386.079 us; speedup vs baseline: 1.0489x; 1.0489x over previous
//
#include <hip/hip_runtime.h>
#include <cmath>

#define SS 45
#define FSPLIT 16

typedef __attribute__((ext_vector_type(8))) _Float16 half8;
typedef __attribute__((ext_vector_type(4))) float float4v;
typedef __attribute__((ext_vector_type(8))) unsigned short ushort8v;

__device__ inline unsigned short f16b(float f) {
    union { _Float16 h; unsigned short u; } c;
    c.h = (_Float16)f;
    return c.u;
}
__device__ inline float f16back(unsigned short u) {
    union { _Float16 h; unsigned short u; } c;
    c.u = u;
    return (float)c.h;
}

__device__ __forceinline__ void async16(const void* g, void* l) {
    __builtin_amdgcn_global_load_lds(
        (const __attribute__((address_space(1))) void*)g,
        (__attribute__((address_space(3))) void*)l, 16, 0, 0);
}

// DPP cross-lane reduce helpers (VALU pipe). 0xB1=xor1, 0x4E=xor2,
// 0x141=row_half_mirror (xor7 within 8), 0x128=row_ror:8 (xor8 within 16).
template <int CTRL>
__device__ __forceinline__ float dppadd(float v) {
    int x = __builtin_amdgcn_mov_dpp(__float_as_int(v), CTRL, 0xF, 0xF, true);
    return v + __int_as_float(x);
}
template <int CTRL>
__device__ __forceinline__ float dppmax(float v) {
    int x = __builtin_amdgcn_mov_dpp(__float_as_int(v), CTRL, 0xF, 0xF, true);
    return fmaxf(v, __int_as_float(x));
}

// monotonic float->uint mapping: order-preserving for all finite floats
__device__ __forceinline__ unsigned int fmono(float f) {
    unsigned int u = __float_as_uint(f);
    return (u & 0x80000000u) ? ~u : (u | 0x80000000u);
}

// ---- W -> WT hi/lo transpose + vmp zero ---------------------------------------
__global__ __launch_bounds__(256) void convW_kernel(
    const float* __restrict__ Wq, const float* __restrict__ Wk, const float* __restrict__ Wv,
    unsigned short* __restrict__ WTh, unsigned short* __restrict__ WTl,
    float* __restrict__ vmp)
{
    int bid = blockIdx.x;
    if (bid < 768) {
        int zy = bid >> 8;
        int bxy = bid & 255;
        const float* W = (zy == 0) ? Wq : (zy == 1) ? Wk : Wv;
        unsigned short* th = WTh + (size_t)zy * 262144;
        unsigned short* tl = WTl + (size_t)zy * 262144;
        __shared__ float t[32][33];
        int bx = bxy & 15, by = bxy >> 4;
        int tx = threadIdx.x & 31, ty = threadIdx.x >> 5;
        for (int i = ty; i < 32; i += 8) t[i][tx] = W[(size_t)(by * 32 + i) * 512 + bx * 32 + tx];
        __syncthreads();
        for (int i = ty; i < 32; i += 8) {
            float f = t[tx][i];
            unsigned short h = f16b(f);
            unsigned short lo = f16b(f - f16back(h));
            th[(size_t)(bx * 32 + i) * 512 + by * 32 + tx] = h;
            tl[(size_t)(bx * 32 + i) * 512 + by * 32 + tx] = lo;
        }
    } else {
        for (int i = threadIdx.x; i < 2048; i += 256) vmp[i] = 0.f;
    }
}

// ---- fused x-conversion + Q,K,V projection + vmean partial --------------------
// EXACT R4 qkv8 (measured ~89-90 us, 6x reproduced). qkv frontier locked.
__global__ __launch_bounds__(512, 2) void qkv8_kernel(
    const float* __restrict__ X,
    const unsigned short* __restrict__ WTh, const unsigned short* __restrict__ WTl,
    float* __restrict__ Q, float* __restrict__ K, float* __restrict__ V,
    float* __restrict__ vmp)
{
    __shared__ unsigned short lds[73728];   // 2 buffers * 36864 shorts (144 KB)

    int wave = threadIdx.x >> 6;            // 0..7
    int lane = threadIdx.x & 63;
    int m0blk = blockIdx.x * 256;
    int n0blk = blockIdx.y * 128;
    int fr = lane & 15;
    int C = lane >> 4;
    int srow = lane >> 2;
    int sslot = lane & 3;
    int mrb = (wave >> 1) * 64;             // 4 wave-rows
    int nrb = (wave & 1) * 64;              // 2 wave-cols

    const unsigned short* gbB[5];
    gbB[0] = WTh;
    gbB[1] = WTl;
    gbB[2] = WTh + 262144;
    gbB[3] = WTl + 262144;
    gbB[4] = WTh + 524288;

    int rloc0 = wave * 32 + srow;
    int rloc1 = wave * 32 + 16 + srow;
    int Cp0 = sslot ^ ((rloc0 >> 1) & 3);
    int Cp1 = sslot ^ ((rloc1 >> 1) & 3);
    const float* xr0 = X + (size_t)(m0blk + rloc0) * 512 + Cp0 * 8;
    const float* xr1 = X + (size_t)(m0blk + rloc1) * 512 + Cp1 * 8;

    float4v accq[4][4], acck[4][4], accv[4][4];
    #pragma unroll
    for (int i = 0; i < 4; i++)
        #pragma unroll
        for (int j = 0; j < 4; j++) {
            accq[i][j] = (float4v){0.f, 0.f, 0.f, 0.f};
            acck[i][j] = (float4v){0.f, 0.f, 0.f, 0.f};
            accv[i][j] = (float4v){0.f, 0.f, 0.f, 0.f};
        }

    auto stageB = [&](int buf, int k0) {
        int rloc = wave * 16 + srow;
        int Cp = sslot ^ ((rloc >> 1) & 3);
        #pragma unroll
        for (int t = 0; t < 5; t++) {
            const unsigned short* g = gbB[t] + (size_t)(n0blk + rloc) * 512 + k0 + Cp * 8;
            async16(g, lds + buf * 36864 + 16384 + t * 4096 + wave * 512);
        }
    };

    float4 xv[2][2];
    auto loadX = [&](int k0) {
        xv[0][0] = *(const float4*)(xr0 + k0);
        xv[0][1] = *(const float4*)(xr0 + k0 + 4);
        xv[1][0] = *(const float4*)(xr1 + k0);
        xv[1][1] = *(const float4*)(xr1 + k0 + 4);
    };
    auto writeA = [&](int buf) {
        #pragma unroll
        for (int inst = 0; inst < 2; inst++) {
            const float* f = (const float*)&xv[inst][0];
            ushort8v hv, lv;
            #pragma unroll
            for (int e = 0; e < 8; e++) {
                unsigned short h = f16b(f[e]);
                hv[e] = h;
                lv[e] = f16b(f[e] - f16back(h));
            }
            unsigned short* dsth = lds + buf * 36864 + (wave * 32 + inst * 16) * 32 + lane * 8;
            *(ushort8v*)dsth = hv;
            *(ushort8v*)(dsth + 8192) = lv;
        }
    };

    // prologue: stage tile 0 fully
    loadX(0);
    stageB(0, 0);
    writeA(0);
    asm volatile("s_waitcnt vmcnt(0)" ::: "memory");
    asm volatile("s_waitcnt lgkmcnt(0)" ::: "memory");
    __builtin_amdgcn_s_barrier();

    for (int kk = 0; kk < 16; kk++) {
        const unsigned short* Lb = lds + (kk & 1) * 36864;
        int nbuf = (kk + 1) & 1;
        int nk0 = (kk + 1) * 32;

        if (kk < 15) {
            loadX(nk0);          // x(k+1) -> regs (HBM latency hides under MFMA)
            stageB(nbuf, nk0);   // B(k+1) -> LDS async
        }

        half8 A_h[4], A_l[4];
        #pragma unroll
        for (int i = 0; i < 4; i++) {
            int R = mrb + i * 16 + fr;
            int sl = C ^ ((R >> 1) & 3);
            A_h[i] = *(const half8*)(Lb + R * 32 + sl * 8);
            A_l[i] = *(const half8*)(Lb + 8192 + R * 32 + sl * 8);
        }
        #pragma unroll
        for (int j = 0; j < 4; j++) {
            int R = nrb + j * 16 + fr;
            int sl = C ^ ((R >> 1) & 3);
            int off = R * 32 + sl * 8;
            half8 Bqh = *(const half8*)(Lb + 16384 + off);
            half8 Bql = *(const half8*)(Lb + 20480 + off);
            half8 Bkh = *(const half8*)(Lb + 24576 + off);
            half8 Bkl = *(const half8*)(Lb + 28672 + off);
            half8 Bvh = *(const half8*)(Lb + 32768 + off);
            #pragma unroll
            for (int i = 0; i < 4; i++) {
                accq[i][j] = __builtin_amdgcn_mfma_f32_16x16x32_f16(A_h[i], Bqh, accq[i][j], 0, 0, 0);
                accq[i][j] = __builtin_amdgcn_mfma_f32_16x16x32_f16(A_h[i], Bql, accq[i][j], 0, 0, 0);
                accq[i][j] = __builtin_amdgcn_mfma_f32_16x16x32_f16(A_l[i], Bqh, accq[i][j], 0, 0, 0);
                acck[i][j] = __builtin_amdgcn_mfma_f32_16x16x32_f16(A_h[i], Bkh, acck[i][j], 0, 0, 0);
                acck[i][j] = __builtin_amdgcn_mfma_f32_16x16x32_f16(A_h[i], Bkl, acck[i][j], 0, 0, 0);
                acck[i][j] = __builtin_amdgcn_mfma_f32_16x16x32_f16(A_l[i], Bkh, acck[i][j], 0, 0, 0);
                accv[i][j] = __builtin_amdgcn_mfma_f32_16x16x32_f16(A_h[i], Bvh, accv[i][j], 0, 0, 0);
            }
        }

        if (kk < 15) {
            writeA(nbuf);        // compiler inserts vmcnt wait for xv regs here
            asm volatile("s_waitcnt vmcnt(0)" ::: "memory");    // B(k+1) landed
            asm volatile("s_waitcnt lgkmcnt(0)" ::: "memory");  // A-writes + reads drained
            __builtin_amdgcn_s_barrier();                       // publish buf k+1
        }
    }

    // ---- vmean partial: sum accv over (i,r), then over C-groups (rows) --------
    int hh = n0blk + nrb;            // col base; one head per wave
    int hd = hh >> 6;                // head index
    int bb0 = (m0blk + mrb) >> 12;   // batch (64-row wave tile never crosses)
    {
        float cs[4];
        #pragma unroll
        for (int j = 0; j < 4; j++) {
            float s = 0.f;
            #pragma unroll
            for (int i = 0; i < 4; i++)
                #pragma unroll
                for (int r = 0; r < 4; r++) s += accv[i][j][r];
            s += __shfl_xor(s, 16, 64);
            s += __shfl_xor(s, 32, 64);
            cs[j] = s;
        }
        if (C == 0) {
            #pragma unroll
            for (int j = 0; j < 4; j++)
                atomicAdd(vmp + ((size_t)(bb0 * 8 + hd) * 64) + j * 16 + fr, cs[j]);
        }
    }

    // ---- epilogue: C/D layout col=lane&15, row=(lane>>4)*4+reg ----------------
    int rbase = C * 4;
    int m0 = m0blk + mrb;
    #pragma unroll
    for (int i = 0; i < 4; i++)
        #pragma unroll
        for (int r = 0; r < 4; r++) {
            int rg = m0 + i * 16 + rbase + r;
            int bb = rg >> 12, l = rg & 4095;
            size_t rowoff = ((size_t)(bb * 8 + hd) * 4096 + l) * 64;
            #pragma unroll
            for (int j = 0; j < 4; j++) Q[rowoff + j * 16 + fr] = accq[i][j][r];
            #pragma unroll
            for (int j = 0; j < 4; j++) K[rowoff + j * 16 + fr] = acck[i][j][r];
            #pragma unroll
            for (int j = 0; j < 4; j++) V[rowoff + j * 16 + fr] = accv[i][j][r];
        }
}

// ---- fused M + per-chunk top-45 (R13) -----------------------------------------
// One 1024-thread block per (bh, 512-query chunk): 256 blocks = 1/CU.
// bh = bid & 31 -> XCD = bid%8 = bh%8: each XCD serves only 4 bh, so the K
// gather working set per XCD is 4 x 1MB = L2 capacity (was ~32MB -> thrash).
// 16 waves x 32 sequential queries each compute M (identical arithmetic ->
// bit-identical), lane 0 deposits sort keys in LDS; then the 512-key bitonic
// top-45 (identical keys -> bit-identical tidx). Kills the 1MB M round-trip
// and one launch.
__global__ __launch_bounds__(1024) void m_topk_kernel(
    const float* __restrict__ Q, const float* __restrict__ K,
    const int* __restrict__ idx, unsigned long long* __restrict__ cand)
{
    __shared__ unsigned long long keys[512];

    int bh = blockIdx.x & 31;
    int c = blockIdx.x >> 5;
    int wave = threadIdx.x >> 6;       // 0..15
    int lane = threadIdx.x & 63;
    int g = lane >> 3;
    int t = lane & 7;
    const float* kb = K + (size_t)bh * 4096 * 64;

    for (int ii = 0; ii < 32; ii++) {
        int l = c * 512 + wave * 32 + ii;
        int inst = bh * 4096 + l;
        float4 qa = *(const float4*)(Q + (size_t)inst * 64 + t * 4);
        float4 qb = *(const float4*)(Q + (size_t)inst * 64 + 32 + t * 4);
        const int* irow = idx + (size_t)l * SS;
        int jv[6];
        #pragma unroll
        for (int it = 0; it < 6; it++) {
            int s = it * 8 + g;
            jv[it] = irow[(it == 5 && g >= 5) ? 0 : s];
        }
        float4 kva[6], kvb[6];
        #pragma unroll
        for (int it = 0; it < 6; it++) {
            kva[it] = *(const float4*)(kb + (size_t)jv[it] * 64 + t * 4);
            kvb[it] = *(const float4*)(kb + (size_t)jv[it] * 64 + 32 + t * 4);
        }
        float maxv = -1e30f, sum = 0.f, p0 = 0.f;
        #pragma unroll
        for (int it = 0; it < 6; it++) {
            float p = qa.x * kva[it].x;
            p = fmaf(qa.y, kva[it].y, p);
            p = fmaf(qa.z, kva[it].z, p);
            p = fmaf(qa.w, kva[it].w, p);
            p = fmaf(qb.x, kvb[it].x, p);
            p = fmaf(qb.y, kvb[it].y, p);
            p = fmaf(qb.z, kvb[it].z, p);
            p = fmaf(qb.w, kvb[it].w, p);
            p = dppadd<0xB1>(p);
            p = dppadd<0x4E>(p);
            p = dppadd<0x141>(p);
            if (it == 0) p0 = p;
            maxv = fmaxf(maxv, p);
            sum += p;
        }
        maxv = dppmax<0x128>(maxv);
        maxv = fmaxf(maxv, __shfl_xor(maxv, 16, 64));
        maxv = fmaxf(maxv, __shfl_xor(maxv, 32, 64));
        sum = dppadd<0x128>(sum);
        sum += __shfl_xor(sum, 16, 64);
        sum += __shfl_xor(sum, 32, 64);
        float p0b = __shfl(p0, 0, 64);
        if (lane == 0) {
            float Mval = maxv - (sum - 3.f * p0b) * (1.f / 45.f);
            keys[wave * 32 + ii] =
                ((unsigned long long)fmono(Mval) << 32) | (unsigned int)(4095 - l);
        }
    }
    __syncthreads();

    int tid = threadIdx.x;
    for (int k = 2; k <= 512; k <<= 1)
        for (int j = k >> 1; j > 0; j >>= 1) {
            if (tid < 512) {
                int i0 = tid;
                int ixj = i0 ^ j;
                if (ixj > i0) {
                    unsigned long long a = keys[i0], b = keys[ixj];
                    bool asc = (i0 & k) != 0;
                    if (asc ? (a > b) : (a < b)) { keys[i0] = b; keys[ixj] = a; }
                }
            }
            __syncthreads();
        }
    if (tid < SS) cand[((size_t)bh * 8 + c) * SS + tid] = keys[tid];
}

// ---------------- topk phase 2: merge 8x45 candidates + base (merged) ----------
__global__ __launch_bounds__(256) void topk_merge_base_kernel(
    const unsigned long long* __restrict__ cand, int* __restrict__ tidx,
    const float* __restrict__ vmp, const float* __restrict__ Wo,
    float* __restrict__ vmean, float* __restrict__ base)
{
    int bid = blockIdx.x;
    int tid = threadIdx.x;
    if (bid < 32) {
        __shared__ unsigned long long keys[512];
        for (int i = tid; i < 512; i += 256) {
            unsigned long long v = 0ull;   // pad: sorts below all real floats
            if (i < 8 * SS) {
                int cc = i / SS, r = i - cc * SS;
                v = cand[((size_t)bid * 8 + cc) * SS + r];
            }
            keys[i] = v;
        }
        __syncthreads();
        for (int k = 2; k <= 512; k <<= 1)
            for (int j = k >> 1; j > 0; j >>= 1) {
                for (int i0 = tid; i0 < 512; i0 += 256) {
                    int ixj = i0 ^ j;
                    if (ixj > i0) {
                        unsigned long long a = keys[i0], b = keys[ixj];
                        bool asc = (i0 & k) != 0;
                        if (asc ? (a > b) : (a < b)) { keys[i0] = b; keys[ixj] = a; }
                    }
                }
                __syncthreads();
            }
        if (tid < SS) tidx[bid * SS + tid] = 4095 - (int)(keys[tid] & 0xFFFFFFFFu);
    } else {
        int b = bid - 32;
        __shared__ float vmS[512];
        for (int i = tid; i < 512; i += 256) {
            float s = vmp[(size_t)b * 512 + i] * (1.f / 4096.f);
            vmS[i] = s;
            vmean[(size_t)b * 512 + i] = s;
        }
        __syncthreads();
        for (int jj = tid; jj < 512; jj += 256) {
            float s = 0.f;
            for (int i = 0; i < 512; i++) s += vmS[i] * Wo[(size_t)i * 512 + jj];
            base[(size_t)b * 512 + jj] = s;
        }
    }
}

// ---------------- flash attention over selected queries + fill (merged) --------
// attn part: R11 structure (256 threads, 16 groups x 3 rows, pad-68).
// fill part: 2048 blocks, 4 float4/thread.
__global__ __launch_bounds__(256) void attn_fill_kernel(
    const float* __restrict__ Q, const float* __restrict__ K, const float* __restrict__ V,
    const int* __restrict__ tidx,
    float* __restrict__ Opart, float* __restrict__ mpart, float* __restrict__ lpart,
    const float4* __restrict__ base4, float4* __restrict__ out4)
{
    int bid = blockIdx.x;
    if (bid >= 512) {
        int i0 = (bid - 512) * 1024 + threadIdx.x;
        #pragma unroll
        for (int k = 0; k < 4; k++) {
            int i = i0 + k * 256;
            int b = i >> 19;
            int j4 = i & 127;
            out4[i] = base4[b * 128 + j4];
        }
        return;
    }
    int split = bid & 15;
    int bh = bid >> 4;
    int L0 = split * (4096 / FSPLIT);

    __shared__ float Qs[48][68];
    __shared__ float Ks[64][68];
    __shared__ float Vs[64][68];
    __shared__ float Ps[48][68];
    __shared__ int tS[48];

    int tid = threadIdx.x;
    int lane = tid & 63, w = tid >> 6;
    if (tid < 48) tS[tid] = (tid < SS) ? tidx[bh * SS + tid] : 0;
    __syncthreads();
    for (int u = w; u < 48; u += 4)
        Qs[u][lane] = Q[((size_t)bh * 4096 + tS[u]) * 64 + lane];

    int ug = tid >> 4, lg = tid & 15;   // 16 groups x 3 rows = 48 queries
    float mrun[3], lrun[3], O[3][4];
    #pragma unroll
    for (int i = 0; i < 3; i++) {
        mrun[i] = -1e30f; lrun[i] = 0.f;
        #pragma unroll
        for (int j = 0; j < 4; j++) O[i][j] = 0.f;
    }

    for (int tt = 0; tt < 4096 / FSPLIT / 64; tt++) {
        int lbase = L0 + tt * 64;
        if (tt > 0) __syncthreads();
        for (int r = w; r < 64; r += 4) {
            Ks[r][lane] = K[((size_t)bh * 4096 + lbase + r) * 64 + lane];
            Vs[r][lane] = V[((size_t)bh * 4096 + lbase + r) * 64 + lane];
        }
        __syncthreads();

        {
            float acc[3][4];
            #pragma unroll
            for (int i = 0; i < 3; i++)
                #pragma unroll
                for (int j = 0; j < 4; j++) acc[i][j] = 0.f;
            for (int d0 = 0; d0 < 64; d0 += 4) {
                float4 a[3], b[4];
                #pragma unroll
                for (int i = 0; i < 3; i++) a[i] = *(float4*)&Qs[ug * 3 + i][d0];
                #pragma unroll
                for (int j = 0; j < 4; j++) b[j] = *(float4*)&Ks[lg * 4 + j][d0];
                #pragma unroll
                for (int i = 0; i < 3; i++)
                    #pragma unroll
                    for (int j = 0; j < 4; j++)
                        acc[i][j] += a[i].x * b[j].x + a[i].y * b[j].y + a[i].z * b[j].z + a[i].w * b[j].w;
            }
            #pragma unroll
            for (int i = 0; i < 3; i++) {
                #pragma unroll
                for (int j = 0; j < 4; j++) acc[i][j] *= 0.125f;
                float tm = fmaxf(fmaxf(acc[i][0], acc[i][1]), fmaxf(acc[i][2], acc[i][3]));
                tm = fmaxf(tm, __shfl_xor(tm, 1, 64));
                tm = fmaxf(tm, __shfl_xor(tm, 2, 64));
                tm = fmaxf(tm, __shfl_xor(tm, 4, 64));
                tm = fmaxf(tm, __shfl_xor(tm, 8, 64));
                float nm = fmaxf(mrun[i], tm);
                float corr = __expf(mrun[i] - nm);
                float rs = 0.f;
                #pragma unroll
                for (int j = 0; j < 4; j++) {
                    float p = __expf(acc[i][j] - nm);
                    Ps[ug * 3 + i][lg * 4 + j] = p;
                    rs += p;
                }
                rs += __shfl_xor(rs, 1, 64);
                rs += __shfl_xor(rs, 2, 64);
                rs += __shfl_xor(rs, 4, 64);
                rs += __shfl_xor(rs, 8, 64);
                lrun[i] = lrun[i] * corr + rs;
                mrun[i] = nm;
                #pragma unroll
                for (int j = 0; j < 4; j++) O[i][j] *= corr;
            }
        }
        __syncthreads();

        {
            for (int l0 = 0; l0 < 64; l0 += 4) {
                float4 vr[4];
                #pragma unroll
                for (int r = 0; r < 4; r++) vr[r] = *(float4*)&Vs[l0 + r][lg * 4];
                #pragma unroll
                for (int i = 0; i < 3; i++) {
                    float4 pv = *(float4*)&Ps[ug * 3 + i][l0];
                    #pragma unroll
                    for (int j = 0; j < 4; j++) {
                        float vj0 = (&vr[0].x)[j], vj1 = (&vr[1].x)[j];
                        float vj2 = (&vr[2].x)[j], vj3 = (&vr[3].x)[j];
                        O[i][j] = fmaf(pv.x, vj0, fmaf(pv.y, vj1, fmaf(pv.z, vj2, fmaf(pv.w, vj3, O[i][j]))));
                    }
                }
            }
        }
    }

    {
        #pragma unroll
        for (int i = 0; i < 3; i++) {
            int u = ug * 3 + i;
            if (u < SS) {
                size_t pbase = ((size_t)(bh * FSPLIT + split) * SS + u);
                if (lg == 0) { mpart[pbase] = mrun[i]; lpart[pbase] = lrun[i]; }
                #pragma unroll
                for (int j = 0; j < 4; j++)
                    Opart[pbase * 64 + lg * 4 + j] = O[i][j];
            }
        }
    }
}

// ---------------- combine splits + delta@Wo + scatter into out -----------------
__global__ __launch_bounds__(256) void combine_kernel(
    const float* __restrict__ Opart, const float* __restrict__ mpart, const float* __restrict__ lpart,
    const float* __restrict__ vmean, const float* __restrict__ Wo,
    const int* __restrict__ tidx, float* __restrict__ out)
{
    int rr = blockIdx.x;
    int bh = rr / SS, u = rr % SS;
    int h = bh & 7, b = bh >> 3;
    __shared__ float dS[64];
    int tid = threadIdx.x;
    if (tid < 64) {
        float m = -1e30f;
        #pragma unroll
        for (int s = 0; s < FSPLIT; s++)
            m = fmaxf(m, mpart[(size_t)(bh * FSPLIT + s) * SS + u]);
        float den = 0.f, num = 0.f;
        #pragma unroll
        for (int s = 0; s < FSPLIT; s++) {
            size_t pbase = (size_t)(bh * FSPLIT + s) * SS + u;
            float wgt = __expf(mpart[pbase] - m);
            den += wgt * lpart[pbase];
            num += wgt * Opart[pbase * 64 + tid];
        }
        dS[tid] = num / den - vmean[(size_t)bh * 64 + tid];
    }
    __syncthreads();
    int l = tidx[rr];
    float* orow = out + ((size_t)b * 4096 + l) * 512;
    for (int j = tid; j < 512; j += 256) {
        float s = 0.f;
        #pragma unroll
        for (int dd = 0; dd < 64; dd++) s += dS[dd] * Wo[(size_t)(h * 64 + dd) * 512 + j];
        atomicAdd(orow + j, s);
    }
}

extern "C" void kernel_launch(void* const* d_in, const int* in_sizes, int n_in,
                              void* d_out, int out_size, void* d_ws, size_t ws_size,
                              hipStream_t stream)
{
    const float* x  = (const float*)d_in[0];
    const float* Wq = (const float*)d_in[1];
    const float* Wk = (const float*)d_in[2];
    const float* Wv = (const float*)d_in[3];
    const float* Wo = (const float*)d_in[4];
    const int*  idx = (const int*)d_in[5];
    float* out = (float*)d_out;

    float* W = (float*)d_ws;
    float* Q = W;                        // 8,388,608 f
    float* K = W + 8388608;              // 8,388,608 f
    float* V = W + 16777216;             // 8,388,608 f
    unsigned short* WTh = (unsigned short*)(W + 33554432);
    unsigned short* WTl = (unsigned short*)(W + 33947648);  // ends 34340864 f
    float* vmp = W + 34340864;           // 2,048 f (live DURING qkv8 -> own space)
    // total 34,342,912 f = 137.4 MB

    float* Opart = W + 25296896;         // 1,474,560
    float* mpart = W + 26771456;         // 23,040
    float* lpart = W + 26794496;         // 23,040
    float* vmean = W + 33439744;         // 2,048
    float* base  = W + 33441792;         // 2,048
    int*   tidx  = (int*)(W + 33443840); // 1,440 ints -> ends 33445280
    unsigned long long* cand = (unsigned long long*)(W + 33445280); // 256*45 u64

    convW_kernel<<<769, 256, 0, stream>>>(Wq, Wk, Wv, WTh, WTl, vmp);
    qkv8_kernel<<<dim3(64, 4), 512, 0, stream>>>(x, WTh, WTl, Q, K, V, vmp);
    m_topk_kernel<<<256, 1024, 0, stream>>>(Q, K, idx, cand);
    topk_merge_base_kernel<<<36, 256, 0, stream>>>(cand, tidx, vmp, Wo, vmean, base);
    attn_fill_kernel<<<512 + 2048, 256, 0, stream>>>(Q, K, V, tidx, Opart, mpart, lpart,
                                                     (const float4*)base, (float4*)out);
    combine_kernel<<<1440, 256, 0, stream>>>(Opart, mpart, lpart, vmean, Wo, tidx, out);
}